// Round 6
// baseline (201.287 us; speedup 1.0000x reference)
//
#include <hip/hip_runtime.h>

// MobileMQA: B=8, C=256, H=W=64, NUM_HEADS=4, hd=64, ds=2
// R13: preamble restructure. GroupNorm is per-channel affine and pooling
//      commutes with it -> never materialize xn. k_prep (one launch):
//      stats + weight-convert + RAW-x bf16 transpose xT[b][n][c] (all
//      independent). k_gemm_kv (256 blocks, 32-m tiles): pooled B-frags
//      built from 4 xT rows + inline affine; K/V layouts identical to R12.
//      k_fused Phase1: B-frags = affine(xT) inline; Phase2/3 = R12 verbatim.
//      k_xnt and xds DELETED (saves 16.8MB x2 traffic + a launch).

#define CNT_INV (1.0f/1048576.0f)
#define EPSV 1e-5f
#define QSCALE 0.18033688f   // 0.125 * log2(e): folded into Q; exp becomes v_exp_f32(S)

// workspace layout (float offsets)
#define WS_STATS 0                    // 64
#define WS_XNT   64                   // bf16 xT  [b][n][c]  = 4,194,304 f
#define WS_K     5242944              // bf16 k   [b][m][d]  = 262,144 f
#define WS_V     5505088              // bf16 v windows      = 262,144 f
#define WS_WQB   5767232              // bf16 wq  [o][c]     = 32,768 f
#define WS_WKV   5800000              // bf16 [wk;wv]        = 16,384 f
#define WS_WOB   5816384              // bf16 wo  [o][c]     = 32,768 f

typedef __attribute__((ext_vector_type(8))) short bf8_t;   // 8 bf16 MFMA A/B frag
typedef __attribute__((ext_vector_type(4))) float f4_t;    // MFMA C/D frag

static __device__ __forceinline__ unsigned fbits(float f) {
  union { float f; unsigned u; } v; v.f = f; return v.u;
}
static __device__ __forceinline__ unsigned short f2bf(float f) {  // RNE-ish
  unsigned u = fbits(f);
  return (unsigned short)((u + 0x7fffu + ((u >> 16) & 1u)) >> 16);
}
static __device__ __forceinline__ unsigned pk_rnd(float a, float b) {
  return __builtin_amdgcn_perm(fbits(b) + 0x8000u, fbits(a) + 0x8000u, 0x07060302u);
}
static __device__ __forceinline__ unsigned pk_tr(float a, float b) {
  return __builtin_amdgcn_perm(fbits(b), fbits(a), 0x07060302u);
}
static __device__ __forceinline__ float bf2f(unsigned short h) {
  union { unsigned u; float f; } v; v.u = ((unsigned)h) << 16; return v.f;
}
static __device__ __forceinline__ float fexp2(float x) {   // 2^x, raw v_exp_f32
  float r; asm("v_exp_f32 %0, %1" : "=v"(r) : "v"(x)); return r;
}

// affine on a raw-x bf8 frag: out[j] = a8[j]*x[j] + b8[j]
static __device__ __forceinline__ bf8_t affine8(bf8_t r, const float* a8, const float* b8) {
  union { bf8_t v; unsigned short u[8]; unsigned w[4]; } in, out;
  in.v = r;
#pragma unroll
  for (int i = 0; i < 4; ++i) {
    float lo = fmaf(bf2f(in.u[2 * i]),     a8[2 * i],     b8[2 * i]);
    float hi = fmaf(bf2f(in.u[2 * i + 1]), a8[2 * i + 1], b8[2 * i + 1]);
    out.w[i] = pk_rnd(lo, hi);
  }
  return out.v;
}

// pooled+affine frag: out[j] = a4[j]*(x00+x01+x10+x11)[j] + b8[j]  (a4 = a/4)
static __device__ __forceinline__ bf8_t pool_affine(bf8_t s00, bf8_t s01, bf8_t s10, bf8_t s11,
                                                    const float* a4, const float* b8) {
  union { bf8_t v; unsigned short u[8]; unsigned w[4]; } x00, x01, x10, x11, out;
  x00.v = s00; x01.v = s01; x10.v = s10; x11.v = s11;
#pragma unroll
  for (int i = 0; i < 4; ++i) {
    float lo = (bf2f(x00.u[2 * i]) + bf2f(x01.u[2 * i])) +
               (bf2f(x10.u[2 * i]) + bf2f(x11.u[2 * i]));
    float hi = (bf2f(x00.u[2 * i + 1]) + bf2f(x01.u[2 * i + 1])) +
               (bf2f(x10.u[2 * i + 1]) + bf2f(x11.u[2 * i + 1]));
    lo = fmaf(lo, a4[2 * i],     b8[2 * i]);
    hi = fmaf(hi, a4[2 * i + 1], b8[2 * i + 1]);
    out.w[i] = pk_rnd(lo, hi);
  }
  return out.v;
}

// ---------------- merged: stats (blk<512) + weights (512..1151) + xT transpose (1152+) ----------------
__global__ __launch_bounds__(256) void k_prep(const float* __restrict__ x,
                                              const float* __restrict__ wq,
                                              const float* __restrict__ wk,
                                              const float* __restrict__ wv,
                                              const float* __restrict__ wo,
                                              float* __restrict__ stats,
                                              unsigned short* __restrict__ wqb,
                                              unsigned short* __restrict__ wkvb,
                                              unsigned short* __restrict__ wob,
                                              unsigned short* __restrict__ xtb) {
  __shared__ unsigned short T[128][72];   // role C transpose tile (chunk-swizzled)
  __shared__ float red[8];                // role A reduction
  const int blk = blockIdx.x;
  const int t = threadIdx.x;
  if (blk < 512) {
    const int b = blk >> 6;
    const int chunk = blk & 63;
    const float4* xb = (const float4*)(x + (size_t)b * 1048576 + (size_t)chunk * 16384);
    float s = 0.f, s2 = 0.f;
#pragma unroll
    for (int it = 0; it < 16; ++it) {
      float4 v = xb[it * 256 + t];
      s  += v.x + v.y + v.z + v.w;
      s2 += v.x * v.x + v.y * v.y + v.z * v.z + v.w * v.w;
    }
#pragma unroll
    for (int o = 32; o > 0; o >>= 1) {
      s  += __shfl_down(s, o);
      s2 += __shfl_down(s2, o);
    }
    const int wid = t >> 6;
    if ((t & 63) == 0) { red[wid] = s; red[4 + wid] = s2; }
    __syncthreads();
    if (t == 0) {
      atomicAdd(&stats[b * 2 + 0], red[0] + red[1] + red[2] + red[3]);
      atomicAdd(&stats[b * 2 + 1], red[4] + red[5] + red[6] + red[7]);
    }
  } else if (blk < 1152) {
    const int idx = (blk - 512) * 256 + t;
    if (idx < 65536) wqb[idx] = f2bf(wq[idx]);
    else if (idx < 81920) wkvb[idx - 65536] = f2bf(wk[idx - 65536]);
    else if (idx < 98304) wkvb[idx - 65536] = f2bf(wv[idx - 81920]);
    else if (idx < 163840) wob[idx - 98304] = f2bf(wo[idx - 98304]);
  } else {
    // raw-x bf16 transpose: xtb[b][n][c]
    const int idx = blk - 1152;                 // 1024 blocks
    const int hp = idx & 31, cq = (idx >> 5) & 3, b = idx >> 7;
    const int c0 = cq * 64, n0 = hp * 128;
    const int n4 = (t & 31) * 4, cl = t >> 5;
    const int wswz = t & 7;                     // (row>>2)&7 for rows n4..n4+3
#pragma unroll
    for (int p = 0; p < 8; ++p) {
      const int c = c0 + p * 8 + cl;
      const int pc = (p ^ wswz) * 8 + cl;
      float4 v = *(const float4*)&x[(size_t)(b * 256 + c) * 4096 + n0 + n4];
      T[n4 + 0][pc] = f2bf(v.x);
      T[n4 + 1][pc] = f2bf(v.y);
      T[n4 + 2][pc] = f2bf(v.z);
      T[n4 + 3][pc] = f2bf(v.w);
    }
    __syncthreads();
    {  // write xtb: 128 rows x 64 c
      const int r = t >> 1, cb4 = (t & 1) * 4;
      const int rswz = (t >> 3) & 7;            // (r>>2)&7
      unsigned short* dst = xtb + ((size_t)b * 4096 + n0 + r) * 256 + c0 + cb4 * 8;
#pragma unroll
      for (int u = 0; u < 4; ++u)
        *(uint4*)(dst + u * 8) = *(const uint4*)&T[r][((cb4 + u) ^ rswz) * 8];
    }
  }
}

// ---------------- K/V gemm: pooled B-frags from xT + inline affine ----------------
// 32-m tiles, grid (32, 8) = 256 blocks. Outputs (R12 layouts):
//   kbf: [b][m][64 d], 16B d-chunk phys = logical ^ (m&7)
//   vtbf: [b][win(m/32)][d(64)][m(32)] — 4KB contiguous windows
__global__ __launch_bounds__(256) void k_gemm_kv(const unsigned short* __restrict__ wkvb,
                                                 const unsigned short* __restrict__ xtb,
                                                 const float* __restrict__ gnw,
                                                 const float* __restrict__ gnb,
                                                 const float* __restrict__ stats,
                                                 unsigned short* __restrict__ kbf,
                                                 unsigned short* __restrict__ vtbf) {
  __shared__ __align__(16) unsigned short kv0[32][72];   // K [m][d]
  __shared__ __align__(16) unsigned short kv1[64][40];   // V [d][m]
  const int t = threadIdx.x;
  const int w = t >> 6, l = t & 63, lane16 = l & 15, quad = l >> 4;
  const int m0 = blockIdx.x * 32, b = blockIdx.y;
  const int kvsel = w >> 1, wh = w & 1;
  const float mu = stats[b * 2 + 0] * CNT_INV;
  const float rstd = rsqrtf(stats[b * 2 + 1] * CNT_INV - mu * mu + EPSV);

  const unsigned short* Abase = wkvb + (size_t)kvsel * 16384 +
                                (size_t)(wh * 32 + lane16) * 256 + quad * 8;
  // per-mg pooled source bases (4 xT rows: n, n+1, n+64, n+65)
  const unsigned short* B00[2];
#pragma unroll
  for (int mg = 0; mg < 2; ++mg) {
    const int m = m0 + mg * 16 + lane16;
    const int nb = (m >> 5) * 128 + (m & 31) * 2;
    B00[mg] = xtb + ((size_t)b * 4096 + nb) * 256 + quad * 8;
  }

  f4_t acc[2][2];
#pragma unroll
  for (int i = 0; i < 2; ++i)
#pragma unroll
    for (int j = 0; j < 2; ++j) acc[i][j] = (f4_t){0.f, 0.f, 0.f, 0.f};

  for (int kc = 0; kc < 256; kc += 32) {
    const int cb = kc + quad * 8;
    float4 g0 = *(const float4*)&gnw[cb];
    float4 g1 = *(const float4*)&gnw[cb + 4];
    float4 h0 = *(const float4*)&gnb[cb];
    float4 h1 = *(const float4*)&gnb[cb + 4];
    float a4[8], b8[8];
    const float gg[8] = {g0.x, g0.y, g0.z, g0.w, g1.x, g1.y, g1.z, g1.w};
    const float hh[8] = {h0.x, h0.y, h0.z, h0.w, h1.x, h1.y, h1.z, h1.w};
#pragma unroll
    for (int j = 0; j < 8; ++j) {
      const float a = gg[j] * rstd;
      a4[j] = a * 0.25f;
      b8[j] = hh[j] - mu * a;
    }
    bf8_t Bf[2];
#pragma unroll
    for (int mg = 0; mg < 2; ++mg) {
      const unsigned short* p = B00[mg] + kc;
      bf8_t s00 = *(const bf8_t*)p;
      bf8_t s01 = *(const bf8_t*)(p + 256);
      bf8_t s10 = *(const bf8_t*)(p + 64 * 256);
      bf8_t s11 = *(const bf8_t*)(p + 65 * 256);
      Bf[mg] = pool_affine(s00, s01, s10, s11, a4, b8);
    }
    bf8_t A[2];
#pragma unroll
    for (int og = 0; og < 2; ++og) A[og] = *(const bf8_t*)(Abase + (size_t)og * 16 * 256 + kc);
#pragma unroll
    for (int og = 0; og < 2; ++og)
#pragma unroll
      for (int mg = 0; mg < 2; ++mg)
        acc[og][mg] = __builtin_amdgcn_mfma_f32_16x16x32_bf16(A[og], Bf[mg], acc[og][mg], 0, 0, 0);
  }

  if (w < 2) {  // K -> kv0[m][d]
#pragma unroll
    for (int og = 0; og < 2; ++og)
#pragma unroll
      for (int mg = 0; mg < 2; ++mg) {
        uint2 p;
        p.x = pk_rnd(acc[og][mg][0], acc[og][mg][1]);
        p.y = pk_rnd(acc[og][mg][2], acc[og][mg][3]);
        *(uint2*)&kv0[mg * 16 + lane16][wh * 32 + og * 16 + quad * 4] = p;
      }
  } else {      // V -> kv1[d][m]
#pragma unroll
    for (int og = 0; og < 2; ++og)
#pragma unroll
      for (int mg = 0; mg < 2; ++mg) {
        const int d0 = wh * 32 + og * 16 + quad * 4;
#pragma unroll
        for (int r = 0; r < 4; ++r)
          kv1[d0 + r][mg * 16 + lane16] = f2bf(acc[og][mg][r]);
      }
  }
  __syncthreads();
  {  // coalesced writeout (each thread: one K uint4 + one V uint4)
    const int rowk = t >> 3, ch = t & 7, e = rowk & 7;
    *(uint4*)(kbf + (size_t)b * 65536 + (size_t)(m0 + rowk) * 64 + ((ch ^ e) * 8)) =
        *(const uint4*)&kv0[rowk][ch * 8];
    const int rowd = t >> 2, q = t & 3;
    *(uint4*)(vtbf + (size_t)b * 65536 + (size_t)(m0 >> 5) * 2048 + (size_t)rowd * 32 + q * 8) =
        *(const uint4*)&kv1[rowd][q * 8];
  }
}

// ---------------- fused Q-proj + attention + WO + residual ----------------
// block = (b, 64-n tile), wave = head. Phase1 B = affine(xT) inline.
// Phase2/3 identical to R12 (kst/vst window staging + plds P-pipeline).
__global__ __launch_bounds__(256) void k_fused(const unsigned short* __restrict__ wqb,
                                               const unsigned short* __restrict__ xtb,
                                               const float* __restrict__ gnw,
                                               const float* __restrict__ gnb,
                                               const float* __restrict__ stats,
                                               const unsigned short* __restrict__ kbf,
                                               const unsigned short* __restrict__ vtbf,
                                               const unsigned short* __restrict__ wob,
                                               const float* __restrict__ x,
                                               const float* __restrict__ gamma,
                                               float* __restrict__ outp) {
  __shared__ __align__(16) unsigned short smem[20480];   // 40,960 B
  __shared__ __align__(16) unsigned short kst[2][2048];  //  8,192 B
  __shared__ __align__(16) unsigned short vst[2][2048];  //  8,192 B
  const int t = threadIdx.x;
  const int w = t >> 6, l = t & 63, lane16 = l & 15, quad = l >> 4;
  const int n0 = blockIdx.x * 64, b = blockIdx.y;
  const int h = w;
  unsigned short* qst = smem + w * 4608;                               // [64][72]
  unsigned short (*plds)[64][40] = (unsigned short (*)[64][40])(smem + w * 5120);
  unsigned short (*aos)[264] = (unsigned short (*)[264])smem;

  const float mu = stats[b * 2 + 0] * CNT_INV;
  const float rstd = rsqrtf(stats[b * 2 + 1] * CNT_INV - mu * mu + EPSV);

  // staging role: waves 0,1 -> K slice halves; waves 2,3 -> V slice halves
  const int sw = w & 1;
  const unsigned short* sbase = (w < 2) ? (kbf + (size_t)b * 65536) : (vtbf + (size_t)b * 65536);
  unsigned short* sdst0 = ((w < 2) ? &kst[0][0] : &vst[0][0]) + sw * 1024 + l * 8;
  unsigned short* sdst1 = ((w < 2) ? &kst[1][0] : &vst[1][0]) + sw * 1024 + l * 8;

#define STAGE_ISSUE(WIN, R0, R1)                                              \
  { const unsigned short* sp = sbase + (size_t)(WIN) * 2048 + sw * 1024 + l * 8; \
    R0 = *(const uint4*)sp; R1 = *(const uint4*)(sp + 512); }
#define STAGE_WRITE(DP, R0, R1)                                               \
  { *(uint4*)(DP) = R0; *(uint4*)((DP) + 512) = R1; }

#define READ_K(BUF, KREG)                                                     \
  {                                                                           \
    _Pragma("unroll")                                                         \
    for (int s = 0; s < 2; ++s) {                                             \
      _Pragma("unroll")                                                       \
      for (int dc = 0; dc < 2; ++dc)                                          \
        KREG[s][dc] = *(const bf8_t*)&kst[BUF][(s * 16 + lane16) * 64 +       \
                                              (((dc * 4 + quad) ^ (lane16 & 7)) * 8)]; \
    }                                                                         \
  }
#define READ_V(BUF, VREG)                                                     \
  {                                                                           \
    _Pragma("unroll")                                                         \
    for (int dg = 0; dg < 4; ++dg)                                            \
      VREG[dg] = *(const bf8_t*)&vst[BUF][(dg * 16 + lane16) * 32 + quad * 8]; \
  }

  // ---- Phase 1: Q-proj 64q x 64d for this head (B = affine(xT)), restage via LDS ----
  {
    const unsigned short* Abase = wqb + (size_t)(h * 64 + lane16) * 256 + quad * 8;
    const unsigned short* Bbase = xtb + ((size_t)b * 4096 + n0 + lane16) * 256 + quad * 8;
    f4_t qacc[4][4];
#pragma unroll
    for (int i = 0; i < 4; ++i)
#pragma unroll
      for (int j = 0; j < 4; ++j) qacc[i][j] = (f4_t){0.f, 0.f, 0.f, 0.f};
    for (int kc = 0; kc < 256; kc += 32) {
      const int cb = kc + quad * 8;
      float4 g0 = *(const float4*)&gnw[cb];
      float4 g1 = *(const float4*)&gnw[cb + 4];
      float4 h0 = *(const float4*)&gnb[cb];
      float4 h1 = *(const float4*)&gnb[cb + 4];
      float a8[8], b8[8];
      const float gg[8] = {g0.x, g0.y, g0.z, g0.w, g1.x, g1.y, g1.z, g1.w};
      const float hh[8] = {h0.x, h0.y, h0.z, h0.w, h1.x, h1.y, h1.z, h1.w};
#pragma unroll
      for (int j = 0; j < 8; ++j) {
        a8[j] = gg[j] * rstd;
        b8[j] = hh[j] - mu * a8[j];
      }
      bf8_t A[4], Bf[4];
#pragma unroll
      for (int og = 0; og < 4; ++og) A[og] = *(const bf8_t*)(Abase + (size_t)og * 16 * 256 + kc);
#pragma unroll
      for (int ng = 0; ng < 4; ++ng) {
        bf8_t raw = *(const bf8_t*)(Bbase + (size_t)ng * 16 * 256 + kc);
        Bf[ng] = affine8(raw, a8, b8);
      }
#pragma unroll
      for (int og = 0; og < 4; ++og)
#pragma unroll
        for (int ng = 0; ng < 4; ++ng)
          qacc[og][ng] = __builtin_amdgcn_mfma_f32_16x16x32_bf16(A[og], Bf[ng], qacc[og][ng], 0, 0, 0);
    }
    // C-layout (row d = og*16+quad*4+r, col q = ng*16+lane16) -> qst[q][d]
#pragma unroll
    for (int og = 0; og < 4; ++og)
#pragma unroll
      for (int ng = 0; ng < 4; ++ng) {
        uint2 p;
        p.x = pk_rnd(qacc[og][ng][0] * QSCALE, qacc[og][ng][1] * QSCALE);
        p.y = pk_rnd(qacc[og][ng][2] * QSCALE, qacc[og][ng][3] * QSCALE);
        *(uint2*)&qst[(ng * 16 + lane16) * 72 + og * 16 + quad * 4] = p;
      }
  }
  bf8_t Qf[4][2];
#pragma unroll
  for (int qg = 0; qg < 4; ++qg)
#pragma unroll
    for (int dc = 0; dc < 2; ++dc)
      Qf[qg][dc] = *(const bf8_t*)&qst[(qg * 16 + lane16) * 72 + dc * 32 + quad * 8];
  __syncthreads();   // all waves read Q before plds overwrites qst space

  // ---- Phase 2: pipelined attention (PV lags S by one KV step) ----
  f4_t O[4][4];
#pragma unroll
  for (int dg = 0; dg < 4; ++dg)
#pragma unroll
    for (int qg = 0; qg < 4; ++qg) O[dg][qg] = (f4_t){0.f, 0.f, 0.f, 0.f};
  f4_t O4[4];
#pragma unroll
  for (int qg = 0; qg < 4; ++qg) O4[qg] = (f4_t){0.f, 0.f, 0.f, 0.f};
  const short onebf = (lane16 == 0) ? (short)0x3F80 : (short)0;
  const bf8_t Aone = {onebf, onebf, onebf, onebf, onebf, onebf, onebf, onebf};

#define SSTEP(KREG, BUF)                                                      \
  {                                                                           \
    _Pragma("unroll")                                                         \
    for (int qg = 0; qg < 4; ++qg) {                                          \
      _Pragma("unroll")                                                       \
      for (int s = 0; s < 2; ++s) {                                           \
        f4_t S = (f4_t){0.f, 0.f, 0.f, 0.f};                                  \
        S = __builtin_amdgcn_mfma_f32_16x16x32_bf16(KREG[s][0], Qf[qg][0], S, 0, 0, 0); \
        S = __builtin_amdgcn_mfma_f32_16x16x32_bf16(KREG[s][1], Qf[qg][1], S, 0, 0, 0); \
        float e0 = fexp2(S[0]);                                               \
        float e1 = fexp2(S[1]);                                               \
        float e2 = fexp2(S[2]);                                               \
        float e3 = fexp2(S[3]);                                               \
        uint2 p; p.x = pk_tr(e0, e1); p.y = pk_tr(e2, e3);                    \
        *(uint2*)&plds[BUF][qg * 16 + lane16][s * 16 + quad * 4] = p;         \
      }                                                                       \
    }                                                                         \
  }

  // prologue: stage windows 0 and 1
  {
    uint4 a0, a1, b0, b1;
    STAGE_ISSUE(0, a0, a1);
    STAGE_ISSUE(1, b0, b1);
    STAGE_WRITE(sdst0, a0, a1);
    STAGE_WRITE(sdst1, b0, b1);
  }
  __syncthreads();   // buf0 + buf1 ready

  bf8_t Kc[2][2], Vc[4];
  READ_K(0, Kc);
  SSTEP(Kc, 0);
  READ_V(0, Vc);
  __syncthreads();   // all waves done reading buf0 before iter1 overwrites it

  for (int it = 1; it < 32; ++it) {
    const int cur = it & 1, pb = cur ^ 1;
    uint4 g0, g1;
    if (it < 31) STAGE_ISSUE(it + 1, g0, g1);
    bf8_t Pf[4];
#pragma unroll
    for (int qg = 0; qg < 4; ++qg)
      Pf[qg] = *(const bf8_t*)&plds[pb][qg * 16 + lane16][quad * 8];
    READ_K(cur, Kc);
    bf8_t Vn[4];
    READ_V(cur, Vn);
    __builtin_amdgcn_s_setprio(1);
#pragma unroll
    for (int dg = 0; dg < 4; ++dg)
#pragma unroll
      for (int qg = 0; qg < 4; ++qg)
        O[dg][qg] = __builtin_amdgcn_mfma_f32_16x16x32_bf16(Vc[dg], Pf[qg], O[dg][qg], 0, 0, 0);
#pragma unroll
    for (int qg = 0; qg < 4; ++qg)
      O4[qg] = __builtin_amdgcn_mfma_f32_16x16x32_bf16(Aone, Pf[qg], O4[qg], 0, 0, 0);
    __builtin_amdgcn_s_setprio(0);
    SSTEP(Kc, cur);
#pragma unroll
    for (int dg = 0; dg < 4; ++dg) Vc[dg] = Vn[dg];
    if (it < 31) STAGE_WRITE((cur ? sdst0 : sdst1), g0, g1);   // write into buf pb
    __syncthreads();
  }
  {  // epilogue: PV(31), P in buf 1
    bf8_t Pf[4];
#pragma unroll
    for (int qg = 0; qg < 4; ++qg)
      Pf[qg] = *(const bf8_t*)&plds[1][qg * 16 + lane16][quad * 8];
    __builtin_amdgcn_s_setprio(1);
#pragma unroll
    for (int dg = 0; dg < 4; ++dg)
#pragma unroll
      for (int qg = 0; qg < 4; ++qg)
        O[dg][qg] = __builtin_amdgcn_mfma_f32_16x16x32_bf16(Vc[dg], Pf[qg], O[dg][qg], 0, 0, 0);
#pragma unroll
    for (int qg = 0; qg < 4; ++qg)
      O4[qg] = __builtin_amdgcn_mfma_f32_16x16x32_bf16(Aone, Pf[qg], O4[qg], 0, 0, 0);
    __builtin_amdgcn_s_setprio(0);
  }
#undef SSTEP
#undef STAGE_ISSUE
#undef STAGE_WRITE
#undef READ_K
#undef READ_V

  // den[q] sits in O4[qg][0] of lanes quad==0, col=lane16 -> broadcast via shfl
  float rden[4];
#pragma unroll
  for (int qg = 0; qg < 4; ++qg) {
    float d = __shfl(O4[qg][0], lane16);
    rden[qg] = 1.f / d;
  }

  __syncthreads();   // all waves done reading plds before aos overwrites
  // ---- write ao tile: rows n, cols c = h*64 + d ----
#pragma unroll
  for (int dg = 0; dg < 4; ++dg)
#pragma unroll
    for (int qg = 0; qg < 4; ++qg) {
      const int c0 = h * 64 + dg * 16 + quad * 4;
      uint2 p;
      p.x = pk_rnd(O[dg][qg][0] * rden[qg], O[dg][qg][1] * rden[qg]);
      p.y = pk_rnd(O[dg][qg][2] * rden[qg], O[dg][qg][3] * rden[qg]);
      *(uint2*)&aos[qg * 16 + lane16][c0] = p;
    }
  __syncthreads();

  // ---- Phase 3: WO gemm from LDS + residual ----
  {
    const unsigned short* Wbase = wob + (size_t)(w * 64 + lane16) * 256 + quad * 8;
    f4_t acc[4][4];
#pragma unroll
    for (int i = 0; i < 4; ++i)
#pragma unroll
      for (int j = 0; j < 4; ++j) acc[i][j] = (f4_t){0.f, 0.f, 0.f, 0.f};
    for (int kc = 0; kc < 256; kc += 32) {
      bf8_t A[4], Bf[4];
#pragma unroll
      for (int og = 0; og < 4; ++og) A[og] = *(const bf8_t*)(Wbase + (size_t)og * 16 * 256 + kc);
#pragma unroll
      for (int ng = 0; ng < 4; ++ng) Bf[ng] = *(const bf8_t*)&aos[ng * 16 + lane16][kc + quad * 8];
#pragma unroll
      for (int og = 0; og < 4; ++og)
#pragma unroll
        for (int ng = 0; ng < 4; ++ng)
          acc[og][ng] = __builtin_amdgcn_mfma_f32_16x16x32_bf16(A[og], Bf[ng], acc[og][ng], 0, 0, 0);
    }
#pragma unroll
    for (int og = 0; og < 4; ++og) {
      float4 g4 = *(const float4*)&gamma[w * 64 + og * 16 + quad * 4];
      const float g[4] = {g4.x, g4.y, g4.z, g4.w};
#pragma unroll
      for (int ng = 0; ng < 4; ++ng) {
        const int n = n0 + ng * 16 + lane16;
#pragma unroll
        for (int r = 0; r < 4; ++r) {
          const int o = w * 64 + og * 16 + quad * 4 + r;
          const size_t ix = ((size_t)(b * 256 + o)) * 4096 + n;
          outp[ix] = x[ix] + g[r] * acc[og][ng][r];
        }
      }
    }
  }
}

extern "C" void kernel_launch(void* const* d_in, const int* in_sizes, int n_in,
                              void* d_out, int out_size, void* d_ws, size_t ws_size,
                              hipStream_t stream) {
  const float* x     = (const float*)d_in[0];
  const float* gnw   = (const float*)d_in[1];
  const float* gnb   = (const float*)d_in[2];
  const float* wq    = (const float*)d_in[3];
  const float* wk    = (const float*)d_in[4];
  const float* wv    = (const float*)d_in[5];
  const float* wo    = (const float*)d_in[6];
  const float* gamma = (const float*)d_in[7];
  float* out = (float*)d_out;
  float* ws  = (float*)d_ws;
  unsigned short* xtb  = (unsigned short*)(ws + WS_XNT);
  unsigned short* kbf  = (unsigned short*)(ws + WS_K);
  unsigned short* vtbf = (unsigned short*)(ws + WS_V);
  unsigned short* wqb  = (unsigned short*)(ws + WS_WQB);
  unsigned short* wkvb = (unsigned short*)(ws + WS_WKV);
  unsigned short* wob  = (unsigned short*)(ws + WS_WOB);

  hipMemsetAsync(ws, 0, 256, stream);
  k_prep<<<2176, 256, 0, stream>>>(x, wq, wk, wv, wo, ws + WS_STATS, wqb, wkvb, wob, xtb);
  k_gemm_kv<<<dim3(32, 8), 256, 0, stream>>>(wkvb, xtb, gnw, gnb, ws + WS_STATS, kbf, vtbf);
  k_fused<<<dim3(64, 8), 256, 0, stream>>>(wqb, xtb, gnw, gnb, ws + WS_STATS, kbf, vtbf, wob, x, gamma, out);
}